// Round 1
// baseline (787.194 us; speedup 1.0000x reference)
//
#include <hip/hip_runtime.h>

#define N_NODES 1024
#define N_EDGES 32768
#define FLAT    4096          // 4*N
#define KC      128           // k-chunk per GEMV block
#define EB      1024          // e-columns per GEMV block (256 thr * float4)

// ---------------------------------------------------------------- init
// agg (ws) <- 0 ; logits (d_out[0..E)) <- bp
__global__ __launch_bounds__(256) void init_ws_k(const float* __restrict__ bp,
                                                 float* __restrict__ agg,
                                                 float* __restrict__ logits) {
    int i = blockIdx.x * 256 + threadIdx.x;
    if (i < FLAT) agg[i] = 0.f;
    if (i < N_EDGES) logits[i] = bp[i];
}

// ---------------------------------------------------------------- EdgeConv
// one thread per edge; h = concat([x_d, x_s - x_d]) is one-hot-sparse:
// h@w1 = w1[td] - w1[N+td] (if td>=0) + w1[N+ts] (if ts>=0)
__global__ __launch_bounds__(256) void edge_conv_k(const int* __restrict__ tn,
                                                   const int* __restrict__ ei,
                                                   const float* __restrict__ w1,
                                                   const float* __restrict__ b1,
                                                   const float* __restrict__ w2,
                                                   const float* __restrict__ b2,
                                                   float* __restrict__ agg) {
    int e = blockIdx.x * 256 + threadIdx.x;
    if (e >= N_EDGES) return;
    int s = ei[e];             // edge_index[0][e]  (source)
    int d = ei[N_EDGES + e];   // edge_index[1][e]  (dest = aggregation node)
    int ts = tn[s];
    int td = tn[d];

    float h[10];
#pragma unroll
    for (int j = 0; j < 10; ++j) h[j] = b1[j];
    if (td >= 0) {
#pragma unroll
        for (int j = 0; j < 10; ++j)
            h[j] += w1[td * 10 + j] - w1[(N_NODES + td) * 10 + j];
    }
    if (ts >= 0) {
#pragma unroll
        for (int j = 0; j < 10; ++j)
            h[j] += w1[(N_NODES + ts) * 10 + j];
    }
#pragma unroll
    for (int j = 0; j < 10; ++j) h[j] = fmaxf(h[j], 0.f);

    float z[4];
#pragma unroll
    for (int c = 0; c < 4; ++c) z[c] = b2[c];
#pragma unroll
    for (int j = 0; j < 10; ++j) {
        float hj = h[j];
#pragma unroll
        for (int c = 0; c < 4; ++c) z[c] += hj * w2[j * 4 + c];
    }
    float m = fmaxf(fmaxf(z[0], z[1]), fmaxf(z[2], z[3]));
    float sum = 0.f;
#pragma unroll
    for (int c = 0; c < 4; ++c) { z[c] = __expf(z[c] - m); sum += z[c]; }
    float inv = 1.f / sum;
#pragma unroll
    for (int c = 0; c < 4; ++c) atomicAdd(&agg[d * 4 + c], z[c] * inv);
}

// ---------------------------------------------------------------- policy GEMV
// logits[e] += sum_{k in chunk} flat[k] * wp[k*E + e]
// grid = (E/EB, FLAT/KC); each thread owns 4 consecutive e (float4 stream).
__global__ __launch_bounds__(256) void policy_gemv_k(const float* __restrict__ flat,
                                                     const float* __restrict__ wp,
                                                     float* __restrict__ logits) {
    __shared__ float sf[KC];
    const int kc = blockIdx.y;
    const int eb = blockIdx.x;
    const int t  = threadIdx.x;
    if (t < KC) sf[t] = flat[kc * KC + t];
    __syncthreads();

    const int e0 = eb * EB + t * 4;
    const float* p = wp + (size_t)(kc * KC) * N_EDGES + e0;
    float ax = 0.f, ay = 0.f, az = 0.f, aw = 0.f;
#pragma unroll 8
    for (int k = 0; k < KC; ++k) {
        float4 w = *reinterpret_cast<const float4*>(p);
        float f = sf[k];
        ax += f * w.x; ay += f * w.y; az += f * w.z; aw += f * w.w;
        p += N_EDGES;
    }
    atomicAdd(&logits[e0 + 0], ax);
    atomicAdd(&logits[e0 + 1], ay);
    atomicAdd(&logits[e0 + 2], az);
    atomicAdd(&logits[e0 + 3], aw);
}

// ---------------------------------------------------------------- value head
__global__ __launch_bounds__(1024) void value_head_k(const float* __restrict__ flat,
                                                     const float* __restrict__ wv1,
                                                     const float* __restrict__ bv1,
                                                     const float* __restrict__ wv2,
                                                     const float* __restrict__ bv2,
                                                     const float* __restrict__ wv3,
                                                     const float* __restrict__ bv3,
                                                     const float* __restrict__ wv4,
                                                     const float* __restrict__ bv4,
                                                     float* __restrict__ out) {
    __shared__ float sflat[FLAT];
    __shared__ float part[16][64];
    __shared__ float sv1[64], sv2[32], sv3[16];
    const int t = threadIdx.x;
    for (int i = t; i < FLAT; i += 1024) sflat[i] = flat[i];
    __syncthreads();

    // layer 1: [4096] x [4096,64] ; 16 k-groups x 64 outputs
    const int g = t >> 6, o = t & 63;
    float acc = 0.f;
    const int k0 = g * 256;
    for (int k = k0; k < k0 + 256; ++k)
        acc += sflat[k] * wv1[(size_t)k * 64 + o];
    part[g][o] = acc;
    __syncthreads();

    if (t < 64) {
        float v = bv1[t];
#pragma unroll
        for (int gg = 0; gg < 16; ++gg) v += part[gg][t];
        sv1[t] = fmaxf(v, 0.f);
    }
    __syncthreads();
    if (t < 32) {
        float v = bv2[t];
#pragma unroll
        for (int j = 0; j < 64; ++j) v += sv1[j] * wv2[j * 32 + t];
        sv2[t] = fmaxf(v, 0.f);
    }
    __syncthreads();
    if (t < 16) {
        float v = bv3[t];
#pragma unroll
        for (int j = 0; j < 32; ++j) v += sv2[j] * wv3[j * 16 + t];
        sv3[t] = fmaxf(v, 0.f);
    }
    __syncthreads();
    if (t == 0) {
        float v = bv4[0];
#pragma unroll
        for (int j = 0; j < 16; ++j) v += sv3[j] * wv4[j];
        out[N_EDGES] = v;   // value scalar after policy
    }
}

// ---------------------------------------------------------------- softmax (in place over d_out[0..E))
__global__ __launch_bounds__(1024) void softmax_policy_k(float* __restrict__ logits) {
    __shared__ float red[16];
    const int t = threadIdx.x;

    // ---- max
    float m = -1e30f;
    for (int i = t; i < N_EDGES; i += 1024) m = fmaxf(m, logits[i]);
#pragma unroll
    for (int o = 32; o > 0; o >>= 1) m = fmaxf(m, __shfl_xor(m, o));
    if ((t & 63) == 0) red[t >> 6] = m;
    __syncthreads();
    if (t < 16) {
        m = red[t];
#pragma unroll
        for (int o = 8; o > 0; o >>= 1) m = fmaxf(m, __shfl_xor(m, o));
        red[t] = m;
    }
    __syncthreads();
    m = red[0];
    __syncthreads();

    // ---- sum of exp
    float s = 0.f;
    for (int i = t; i < N_EDGES; i += 1024) s += __expf(logits[i] - m);
#pragma unroll
    for (int o = 32; o > 0; o >>= 1) s += __shfl_xor(s, o);
    if ((t & 63) == 0) red[t >> 6] = s;
    __syncthreads();
    if (t < 16) {
        s = red[t];
#pragma unroll
        for (int o = 8; o > 0; o >>= 1) s += __shfl_xor(s, o);
        red[t] = s;
    }
    __syncthreads();
    const float inv = 1.f / red[0];

    // ---- write (in-place; each index touched by exactly one thread)
    for (int i = t; i < N_EDGES; i += 1024)
        logits[i] = __expf(logits[i] - m) * inv;
}

// ---------------------------------------------------------------- launch
extern "C" void kernel_launch(void* const* d_in, const int* in_sizes, int n_in,
                              void* d_out, int out_size, void* d_ws, size_t ws_size,
                              hipStream_t stream) {
    const int*   tn  = (const int*)  d_in[0];
    const int*   ei  = (const int*)  d_in[1];
    const float* w1  = (const float*)d_in[2];
    const float* b1  = (const float*)d_in[3];
    const float* w2  = (const float*)d_in[4];
    const float* b2  = (const float*)d_in[5];
    const float* wv1 = (const float*)d_in[6];
    const float* bv1 = (const float*)d_in[7];
    const float* wv2 = (const float*)d_in[8];
    const float* bv2 = (const float*)d_in[9];
    const float* wv3 = (const float*)d_in[10];
    const float* bv3 = (const float*)d_in[11];
    const float* wv4 = (const float*)d_in[12];
    const float* bv4 = (const float*)d_in[13];
    const float* wp  = (const float*)d_in[14];
    const float* bp  = (const float*)d_in[15];

    float* out    = (float*)d_out;      // [E] policy + [1] value
    float* logits = out;                // logits live in d_out[0..E), softmaxed in place
    float* agg    = (float*)d_ws;       // [4096] flat

    init_ws_k<<<N_EDGES / 256, 256, 0, stream>>>(bp, agg, logits);
    edge_conv_k<<<N_EDGES / 256, 256, 0, stream>>>(tn, ei, w1, b1, w2, b2, agg);
    policy_gemv_k<<<dim3(N_EDGES / EB, FLAT / KC), 256, 0, stream>>>(agg, wp, logits);
    value_head_k<<<1, 1024, 0, stream>>>(agg, wv1, bv1, wv2, bv2, wv3, bv3, wv4, bv4, out);
    softmax_policy_k<<<1, 1024, 0, stream>>>(logits);
}